// Round 2
// baseline (895.446 us; speedup 1.0000x reference)
//
#include <hip/hip_runtime.h>
#include <hip/hip_bf16.h>

typedef unsigned short u16;
typedef unsigned int u32;
typedef __attribute__((ext_vector_type(4))) float f32x4;
typedef __attribute__((ext_vector_type(8))) short s16x8;

#define D_MODEL 1024
#define NHEADS 16
#define HD 64
#define SEQ 2048
#define BATCH 4
#define ROWS (BATCH*SEQ)

#define MFMA16 __builtin_amdgcn_mfma_f32_16x16x32_bf16

// round-to-nearest-even f32 -> bf16 (inputs are finite here)
__device__ inline u16 f2bf(float f) {
  u32 u = __builtin_bit_cast(u32, f);
  u32 r = (u + 0x7fffu + ((u >> 16) & 1u)) >> 16;
  return (u16)r;
}

__device__ inline void gload_lds16(const void* g, void* l) {
  __builtin_amdgcn_global_load_lds((const __attribute__((address_space(1))) void*)g,
                                   (__attribute__((address_space(3))) void*)l,
                                   16, 0, 0);
}

// ---------------- small kernels ----------------

__global__ __launch_bounds__(256) void cast_f32_bf16(const float* __restrict__ src,
                                                     u16* __restrict__ dst, int n4) {
  int i = blockIdx.x * 256 + threadIdx.x;
  if (i >= n4) return;
  float4 v = ((const float4*)src)[i];
  union { u16 s[4]; unsigned long long ll; } o;
  o.s[0] = f2bf(v.x); o.s[1] = f2bf(v.y); o.s[2] = f2bf(v.z); o.s[3] = f2bf(v.w);
  ((unsigned long long*)dst)[i] = o.ll;
}

__global__ __launch_bounds__(256) void row_u(const float* __restrict__ x,
                                             const float* __restrict__ dx,
                                             float* __restrict__ usum) {
  int row = blockIdx.x;
  int tid = threadIdx.x;
  const float4* xr = (const float4*)(x + (size_t)row * D_MODEL);
  const float4* dr = (const float4*)(dx + (size_t)row * D_MODEL);
  float4 a = xr[tid], d = dr[tid];
  float sx = a.x*a.x + a.y*a.y + a.z*a.z + a.w*a.w;
  float sd = d.x*d.x + d.y*d.y + d.z*d.z + d.w*d.w;
  #pragma unroll
  for (int m = 1; m < 64; m <<= 1) { sx += __shfl_xor(sx, m); sd += __shfl_xor(sd, m); }
  __shared__ float rx[4], rd[4];
  int wave = tid >> 6;
  if ((tid & 63) == 0) { rx[wave] = sx; rd[wave] = sd; }
  __syncthreads();
  if (tid == 0) {
    float SX = rx[0]+rx[1]+rx[2]+rx[3];
    float SD = rd[0]+rd[1]+rd[2]+rd[3];
    float u = sqrtf(SD) / (sqrtf(SX) + 1e-8f);
    atomicAdd(&usum[row >> 11], u);
  }
}

__global__ __launch_bounds__(256) void pm_rowmean_k(const float* __restrict__ pm,
                                                    float* __restrict__ pmrow) {
  int row = blockIdx.x, tid = threadIdx.x;
  const float4* pr = (const float4*)(pm + (size_t)row * SEQ);
  float4 a = pr[tid*2], b = pr[tid*2+1];
  float s = a.x+a.y+a.z+a.w + b.x+b.y+b.z+b.w;
  #pragma unroll
  for (int m = 1; m < 64; m <<= 1) s += __shfl_xor(s, m);
  __shared__ float rs[4];
  int wave = tid >> 6;
  if ((tid & 63) == 0) rs[wave] = s;
  __syncthreads();
  if (tid == 0) pmrow[row] = (rs[0]+rs[1]+rs[2]+rs[3]) * (1.0f / SEQ);
}

__global__ void lam_k(const float* __restrict__ usum, float* __restrict__ lam) {
  int t = threadIdx.x;
  if (t < BATCH) lam[t] = 10.0f * expf(-5.0f * usum[t] * (1.0f / SEQ));
}

// ---------------- GEMM: C[i][j] = sum_k A[i][k]*Bw[j][k] + bias ----------------
// A:[M][K] bf16 row-major, Bw:[N][K] bf16 row-major (B-transposed layout), K%32==0,
// M%128==0, N%128==0. ROWB: bias indexed by output row (for the swapped Vt GEMM).

__device__ inline void store_o(float* C, size_t i, float v) { C[i] = v; }
__device__ inline void store_o(u16* C, size_t i, float v)   { C[i] = f2bf(v); }

template<typename OutT, bool ROWB>
__global__ __launch_bounds__(256) void gemm_bt(const u16* __restrict__ A,
                                               const u16* __restrict__ Bw,
                                               const float* __restrict__ bias,
                                               OutT* __restrict__ C,
                                               int M, int N, int K) {
  __shared__ __align__(16) u16 As[128*32];
  __shared__ __align__(16) u16 Bs[128*32];
  const int tid = threadIdx.x;
  const int wave = tid >> 6, lane = tid & 63, g = lane >> 4, l15 = lane & 15;
  const int row0 = blockIdx.y * 128, col0 = blockIdx.x * 128;
  const int wr = (wave >> 1) * 64, wc = (wave & 1) * 64;
  f32x4 acc[4][4] = {};
  const int chunk0 = wave * 2048;          // this wave's 2KB of each 8KB tile
  for (int k0 = 0; k0 < K; k0 += 32) {
    #pragma unroll
    for (int c = 0; c < 2; ++c) {
      int chunk = chunk0 + c * 1024;       // wave-uniform LDS base
      int li = chunk + lane * 16;          // per-lane byte
      int r = li >> 6;                     // tile row (64B per row)
      int cb = (li & 63) >> 1;             // u16 offset in row
      const u16* ga = A  + (size_t)(row0 + r) * K + k0 + cb;
      gload_lds16(ga, (char*)As + chunk);
      const u16* gb = Bw + (size_t)(col0 + r) * K + k0 + cb;
      gload_lds16(gb, (char*)Bs + chunk);
    }
    __syncthreads();
    s16x8 af[4], bf[4];
    #pragma unroll
    for (int mi = 0; mi < 4; ++mi) af[mi] = *(const s16x8*)&As[(wr + mi*16 + l15)*32 + g*8];
    #pragma unroll
    for (int ni = 0; ni < 4; ++ni) bf[ni] = *(const s16x8*)&Bs[(wc + ni*16 + l15)*32 + g*8];
    #pragma unroll
    for (int mi = 0; mi < 4; ++mi)
      #pragma unroll
      for (int ni = 0; ni < 4; ++ni)
        acc[mi][ni] = MFMA16(af[mi], bf[ni], acc[mi][ni], 0, 0, 0);
    __syncthreads();
  }
  #pragma unroll
  for (int mi = 0; mi < 4; ++mi) {
    int rbase = row0 + wr + mi*16 + g*4;
    #pragma unroll
    for (int ni = 0; ni < 4; ++ni) {
      int cc = col0 + wc + ni*16 + l15;
      float cbias = ROWB ? 0.0f : bias[cc];
      #pragma unroll
      for (int r = 0; r < 4; ++r) {
        float v = acc[mi][ni][r] + (ROWB ? bias[rbase + r] : cbias);
        store_o(C, (size_t)(rbase + r) * N + cc, v);
      }
    }
  }
}

// ---------------- fused clipping flash attention ----------------
// Q,K: [B,S,H,HD] bf16 (row-major [8192][1024]); Vt: [H*HD][B*S] bf16.
// O out: [B,S,H,HD] bf16. Block: (bh, qt); 4 waves x 32 q-rows.

__global__ __launch_bounds__(256) void attn_k(const u16* __restrict__ Qb,
                                              const u16* __restrict__ Kb,
                                              const u16* __restrict__ Vtb,
                                              const float* __restrict__ pm,
                                              const float* __restrict__ pmrow,
                                              const float* __restrict__ lamp,
                                              u16* __restrict__ Ob) {
  __shared__ __align__(16) u16 Ks[64*64];     // [k][d], XOR-swizzled chunks
  __shared__ __align__(16) u16 Vs[64*64];     // [d][k], XOR-swizzled chunks
  __shared__ __align__(16) u16 Ps[4][32*72];  // per-wave P, pad 72
  const int bh = blockIdx.x, qt = blockIdx.y;
  const int b = bh >> 4, h = bh & 15;
  const int tid = threadIdx.x, wave = tid >> 6, lane = tid & 63;
  const int g = lane >> 4, l15 = lane & 15;
  const float lam = lamp[b];
  const bool clip_en = lam > 1.0f;
  const int q0 = qt * 128 + wave * 32;        // seq-local q base for this wave

  s16x8 qf[2][2];
  #pragma unroll
  for (int mi = 0; mi < 2; ++mi)
    #pragma unroll
    for (int kk = 0; kk < 2; ++kk)
      qf[mi][kk] = *(const s16x8*)&Qb[(size_t)(b*SEQ + q0 + mi*16 + l15)*D_MODEL + h*HD + kk*32 + g*8];

  float thr[2][4], mrow[2][4], lrow[2][4];
  #pragma unroll
  for (int mi = 0; mi < 2; ++mi)
    #pragma unroll
    for (int r = 0; r < 4; ++r) {
      thr[mi][r] = clip_en ? lam * pmrow[q0 + mi*16 + g*4 + r] : -INFINITY;
      mrow[mi][r] = -INFINITY;
      lrow[mi][r] = 0.0f;
    }
  f32x4 oacc[2][4] = {};

  for (int kt = 0; kt < SEQ; kt += 64) {
    #pragma unroll
    for (int c = 0; c < 2; ++c) {
      int chunk = wave * 2048 + c * 1024;     // wave-uniform LDS base
      int li = chunk + lane * 16;
      int r = li >> 7;                        // tile row (128B per row)
      int ccol = (li & 127) >> 4;             // LDS chunk slot 0..7
      int gcol = ((ccol ^ (r & 7)) * 8);      // swizzle-inverse global chunk (elems)
      const u16* gk = Kb  + (size_t)(b*SEQ + kt + r)*D_MODEL + h*HD + gcol;
      gload_lds16(gk, (char*)Ks + chunk);
      const u16* gv = Vtb + (size_t)(h*HD + r)*ROWS + b*SEQ + kt + gcol;
      gload_lds16(gv, (char*)Vs + chunk);
    }
    __syncthreads();

    // S = Q K^T
    f32x4 s[2][4] = {};
    #pragma unroll
    for (int nj = 0; nj < 4; ++nj) {
      int row = nj*16 + l15;
      s16x8 kf0 = *(const s16x8*)((const char*)Ks + row*128 + (((0*4 + g) ^ (row & 7)) * 16));
      s16x8 kf1 = *(const s16x8*)((const char*)Ks + row*128 + (((1*4 + g) ^ (row & 7)) * 16));
      #pragma unroll
      for (int mi = 0; mi < 2; ++mi) {
        s[mi][nj] = MFMA16(qf[mi][0], kf0, s[mi][nj], 0, 0, 0);
        s[mi][nj] = MFMA16(qf[mi][1], kf1, s[mi][nj], 0, 0, 0);
      }
    }

    // bias + clip + online softmax
    #pragma unroll
    for (int mi = 0; mi < 2; ++mi) {
      #pragma unroll
      for (int r = 0; r < 4; ++r) {
        int qrow = q0 + mi*16 + g*4 + r;
        const float* pmr = pm + (size_t)qrow * SEQ + kt;
        float Ls[4];
        #pragma unroll
        for (int nj = 0; nj < 4; ++nj) {
          float Lv = s[mi][nj][r] * 0.125f + lam * pmr[nj*16 + l15];
          if (Lv < thr[mi][r]) Lv = -INFINITY;
          Ls[nj] = Lv;
        }
        float mx = fmaxf(fmaxf(Ls[0], Ls[1]), fmaxf(Ls[2], Ls[3]));
        #pragma unroll
        for (int m = 1; m < 16; m <<= 1) mx = fmaxf(mx, __shfl_xor(mx, m));
        float mnew = fmaxf(mrow[mi][r], mx);
        float scale, rs = 0.0f;
        if (mnew == -INFINITY) {
          scale = 1.0f;
          #pragma unroll
          for (int nj = 0; nj < 4; ++nj) s[mi][nj][r] = 0.0f;
        } else {
          scale = __expf(mrow[mi][r] - mnew);
          #pragma unroll
          for (int nj = 0; nj < 4; ++nj) {
            float p = __expf(Ls[nj] - mnew);
            s[mi][nj][r] = p;
            rs += p;
          }
        }
        #pragma unroll
        for (int m = 1; m < 16; m <<= 1) rs += __shfl_xor(rs, m);
        lrow[mi][r] = lrow[mi][r] * scale + rs;
        mrow[mi][r] = mnew;
        #pragma unroll
        for (int di = 0; di < 4; ++di) oacc[mi][di][r] *= scale;
      }
    }

    // P -> LDS (bf16)
    #pragma unroll
    for (int mi = 0; mi < 2; ++mi)
      #pragma unroll
      for (int r = 0; r < 4; ++r) {
        int prow = mi*16 + g*4 + r;
        #pragma unroll
        for (int nj = 0; nj < 4; ++nj)
          Ps[wave][prow*72 + nj*16 + l15] = f2bf(s[mi][nj][r]);
      }

    // O += P V   (A-frag from Ps, B-frag from Vs)
    s16x8 pf[2][2];
    #pragma unroll
    for (int mi = 0; mi < 2; ++mi)
      #pragma unroll
      for (int kk = 0; kk < 2; ++kk)
        pf[mi][kk] = *(const s16x8*)&Ps[wave][(mi*16 + l15)*72 + kk*32 + g*8];
    s16x8 vf[4][2];
    #pragma unroll
    for (int di = 0; di < 4; ++di) {
      int row = di*16 + l15;
      #pragma unroll
      for (int kk = 0; kk < 2; ++kk)
        vf[di][kk] = *(const s16x8*)((const char*)Vs + row*128 + (((kk*4 + g) ^ (row & 7)) * 16));
    }
    #pragma unroll
    for (int mi = 0; mi < 2; ++mi)
      #pragma unroll
      for (int di = 0; di < 4; ++di)
        #pragma unroll
        for (int kk = 0; kk < 2; ++kk)
          oacc[mi][di] = MFMA16(pf[mi][kk], vf[di][kk], oacc[mi][di], 0, 0, 0);
    __syncthreads();
  }

  #pragma unroll
  for (int mi = 0; mi < 2; ++mi)
    #pragma unroll
    for (int r = 0; r < 4; ++r) {
      float inv = 1.0f / lrow[mi][r];
      size_t rowoff = (size_t)(b*SEQ + q0 + mi*16 + g*4 + r) * D_MODEL + h*HD;
      #pragma unroll
      for (int di = 0; di < 4; ++di)
        Ob[rowoff + di*16 + l15] = f2bf(oacc[mi][di][r] * inv);
    }
}

// ---------------- launcher ----------------

extern "C" void kernel_launch(void* const* d_in, const int* in_sizes, int n_in,
                              void* d_out, int out_size, void* d_ws, size_t ws_size,
                              hipStream_t stream) {
  const float* x  = (const float*)d_in[0];
  const float* pm = (const float*)d_in[1];
  const float* dx = (const float*)d_in[2];
  const float* wq = (const float*)d_in[3];
  const float* bq = (const float*)d_in[4];
  const float* wk = (const float*)d_in[5];
  const float* bk = (const float*)d_in[6];
  const float* wv = (const float*)d_in[7];
  const float* bv = (const float*)d_in[8];
  const float* wo = (const float*)d_in[9];
  const float* bo = (const float*)d_in[10];
  float* out = (float*)d_out;

  char* ws = (char*)d_ws;
  const size_t MB = 1024 * 1024;
  u16* xb   = (u16*)(ws + 0 * MB);
  u16* Qb   = (u16*)(ws + 16 * MB);
  u16* Kb   = (u16*)(ws + 32 * MB);
  u16* Vtb  = (u16*)(ws + 48 * MB);
  u16* Obuf = (u16*)(ws + 64 * MB);
  u16* wqb  = (u16*)(ws + 80 * MB);
  u16* wkb  = (u16*)(ws + 82 * MB);
  u16* wvb  = (u16*)(ws + 84 * MB);
  u16* wob  = (u16*)(ws + 86 * MB);
  float* pmrow = (float*)(ws + 88 * MB);
  float* usum  = (float*)(ws + 88 * MB + 16384);
  float* lam   = (float*)(ws + 88 * MB + 16384 + 64);

  hipMemsetAsync(usum, 0, 16, stream);
  cast_f32_bf16<<<8192, 256, 0, stream>>>(x,  xb,  ROWS * D_MODEL / 4);
  cast_f32_bf16<<<1024, 256, 0, stream>>>(wq, wqb, D_MODEL * D_MODEL / 4);
  cast_f32_bf16<<<1024, 256, 0, stream>>>(wk, wkb, D_MODEL * D_MODEL / 4);
  cast_f32_bf16<<<1024, 256, 0, stream>>>(wv, wvb, D_MODEL * D_MODEL / 4);
  cast_f32_bf16<<<1024, 256, 0, stream>>>(wo, wob, D_MODEL * D_MODEL / 4);
  row_u<<<ROWS, 256, 0, stream>>>(x, dx, usum);
  pm_rowmean_k<<<SEQ, 256, 0, stream>>>(pm, pmrow);
  lam_k<<<1, 64, 0, stream>>>(usum, lam);

  // Q = x wq^T + bq ; K = x wk^T + bk   -> [8192][1024] bf16
  gemm_bt<u16, false><<<dim3(8, 64), 256, 0, stream>>>(xb, wqb, bq, Qb, ROWS, D_MODEL, D_MODEL);
  gemm_bt<u16, false><<<dim3(8, 64), 256, 0, stream>>>(xb, wkb, bk, Kb, ROWS, D_MODEL, D_MODEL);
  // Vt[j][i] = sum_k wv[j][k] x[i][k] + bv[j]  -> [1024][8192] bf16 (V transposed)
  gemm_bt<u16, true ><<<dim3(64, 8), 256, 0, stream>>>(wvb, xb, bv, Vtb, D_MODEL, ROWS, D_MODEL);

  attn_k<<<dim3(64, 16), 256, 0, stream>>>(Qb, Kb, Vtb, pm, pmrow, lam, Obuf);

  // out = O wo^T + bo  (f32 out)
  gemm_bt<float, false><<<dim3(8, 64), 256, 0, stream>>>(Obuf, wob, bo, out, ROWS, D_MODEL, D_MODEL);
}

// Round 3
// 614.615 us; speedup vs baseline: 1.4569x; 1.4569x over previous
//
#include <hip/hip_runtime.h>
#include <hip/hip_bf16.h>

typedef unsigned short u16;
typedef unsigned int u32;
typedef unsigned long long u64;
typedef __attribute__((ext_vector_type(4))) float f32x4;
typedef __attribute__((ext_vector_type(8))) short s16x8;

#define D_MODEL 1024
#define NHEADS 16
#define HD 64
#define SEQ 2048
#define BATCH 4
#define ROWS (BATCH*SEQ)

#define MFMA16 __builtin_amdgcn_mfma_f32_16x16x32_bf16

// round-to-nearest-even f32 -> bf16
__device__ inline u16 f2bf(float f) {
  u32 u = __builtin_bit_cast(u32, f);
  u32 r = (u + 0x7fffu + ((u >> 16) & 1u)) >> 16;
  return (u16)r;
}

// pack 2 f32 -> 1 dword of 2 bf16 (RNE), T12 recipe
__device__ inline u32 cvt_pk_bf16(float lo, float hi) {
  u32 r;
  asm volatile("v_cvt_pk_bf16_f32 %0, %1, %2" : "=v"(r) : "v"(lo), "v"(hi));
  return r;
}

__device__ inline void gload_lds16(const void* g, void* l) {
  __builtin_amdgcn_global_load_lds((const __attribute__((address_space(1))) void*)g,
                                   (__attribute__((address_space(3))) void*)l,
                                   16, 0, 0);
}

// ---------------- small kernels ----------------

__global__ __launch_bounds__(256) void cast_f32_bf16(const float* __restrict__ src,
                                                     u16* __restrict__ dst, int n4) {
  int i = blockIdx.x * 256 + threadIdx.x;
  if (i >= n4) return;
  float4 v = ((const float4*)src)[i];
  union { u16 s[4]; u64 ll; } o;
  o.s[0] = f2bf(v.x); o.s[1] = f2bf(v.y); o.s[2] = f2bf(v.z); o.s[3] = f2bf(v.w);
  ((u64*)dst)[i] = o.ll;
}

__global__ __launch_bounds__(256) void row_u(const float* __restrict__ x,
                                             const float* __restrict__ dx,
                                             float* __restrict__ usum) {
  int row = blockIdx.x;
  int tid = threadIdx.x;
  const float4* xr = (const float4*)(x + (size_t)row * D_MODEL);
  const float4* dr = (const float4*)(dx + (size_t)row * D_MODEL);
  float4 a = xr[tid], d = dr[tid];
  float sx = a.x*a.x + a.y*a.y + a.z*a.z + a.w*a.w;
  float sd = d.x*d.x + d.y*d.y + d.z*d.z + d.w*d.w;
  #pragma unroll
  for (int m = 1; m < 64; m <<= 1) { sx += __shfl_xor(sx, m); sd += __shfl_xor(sd, m); }
  __shared__ float rx[4], rd[4];
  int wave = tid >> 6;
  if ((tid & 63) == 0) { rx[wave] = sx; rd[wave] = sd; }
  __syncthreads();
  if (tid == 0) {
    float SX = rx[0]+rx[1]+rx[2]+rx[3];
    float SD = rd[0]+rd[1]+rd[2]+rd[3];
    float u = sqrtf(SD) / (sqrtf(SX) + 1e-8f);
    atomicAdd(&usum[row >> 11], u);
  }
}

__global__ __launch_bounds__(256) void pm_rowmean_k(const float* __restrict__ pm,
                                                    float* __restrict__ pmrow) {
  int row = blockIdx.x, tid = threadIdx.x;
  const float4* pr = (const float4*)(pm + (size_t)row * SEQ);
  float4 a = pr[tid*2], b = pr[tid*2+1];
  float s = a.x+a.y+a.z+a.w + b.x+b.y+b.z+b.w;
  #pragma unroll
  for (int m = 1; m < 64; m <<= 1) s += __shfl_xor(s, m);
  __shared__ float rs[4];
  int wave = tid >> 6;
  if ((tid & 63) == 0) rs[wave] = s;
  __syncthreads();
  if (tid == 0) pmrow[row] = (rs[0]+rs[1]+rs[2]+rs[3]) * (1.0f / SEQ);
}

__global__ void lam_k(const float* __restrict__ usum, float* __restrict__ lam) {
  int t = threadIdx.x;
  if (t < BATCH) lam[t] = 10.0f * expf(-5.0f * usum[t] * (1.0f / SEQ));
}

// ---------------- GEMM: C[i][j] = sum_k A[i][k]*Bw[j][k] + bias ----------------

__device__ inline void store_o(float* C, size_t i, float v) { C[i] = v; }
__device__ inline void store_o(u16* C, size_t i, float v)   { C[i] = f2bf(v); }

template<typename OutT, bool ROWB>
__global__ __launch_bounds__(256) void gemm_bt(const u16* __restrict__ A,
                                               const u16* __restrict__ Bw,
                                               const float* __restrict__ bias,
                                               OutT* __restrict__ C,
                                               int M, int N, int K) {
  __shared__ __align__(16) u16 As[128*32];
  __shared__ __align__(16) u16 Bs[128*32];
  const int tid = threadIdx.x;
  const int wave = tid >> 6, lane = tid & 63, g = lane >> 4, l15 = lane & 15;
  // XCD-aware swizzle (nwg % 8 == 0 for all our grids)
  const int id0 = blockIdx.y * gridDim.x + blockIdx.x;
  const int cpx = (gridDim.x * gridDim.y) >> 3;
  const int id = (id0 & 7) * cpx + (id0 >> 3);
  const int bx = id % gridDim.x, by = id / gridDim.x;
  const int row0 = by * 128, col0 = bx * 128;
  const int wr = (wave >> 1) * 64, wc = (wave & 1) * 64;
  f32x4 acc[4][4] = {};
  const int chunk0 = wave * 2048;
  for (int k0 = 0; k0 < K; k0 += 32) {
    #pragma unroll
    for (int c = 0; c < 2; ++c) {
      int chunk = chunk0 + c * 1024;
      int li = chunk + lane * 16;
      int r = li >> 6;
      int cb = (li & 63) >> 1;
      const u16* ga = A  + (size_t)(row0 + r) * K + k0 + cb;
      gload_lds16(ga, (char*)As + chunk);
      const u16* gb = Bw + (size_t)(col0 + r) * K + k0 + cb;
      gload_lds16(gb, (char*)Bs + chunk);
    }
    __syncthreads();
    s16x8 af[4], bf[4];
    #pragma unroll
    for (int mi = 0; mi < 4; ++mi) af[mi] = *(const s16x8*)&As[(wr + mi*16 + l15)*32 + g*8];
    #pragma unroll
    for (int ni = 0; ni < 4; ++ni) bf[ni] = *(const s16x8*)&Bs[(wc + ni*16 + l15)*32 + g*8];
    __builtin_amdgcn_s_setprio(1);
    #pragma unroll
    for (int mi = 0; mi < 4; ++mi)
      #pragma unroll
      for (int ni = 0; ni < 4; ++ni)
        acc[mi][ni] = MFMA16(af[mi], bf[ni], acc[mi][ni], 0, 0, 0);
    __builtin_amdgcn_s_setprio(0);
    __syncthreads();
  }
  #pragma unroll
  for (int mi = 0; mi < 4; ++mi) {
    int rbase = row0 + wr + mi*16 + g*4;
    #pragma unroll
    for (int ni = 0; ni < 4; ++ni) {
      int cc = col0 + wc + ni*16 + l15;
      float cbias = ROWB ? 0.0f : bias[cc];
      #pragma unroll
      for (int r = 0; r < 4; ++r) {
        float v = acc[mi][ni][r] + (ROWB ? bias[rbase + r] : cbias);
        store_o(C, (size_t)(rbase + r) * N + cc, v);
      }
    }
  }
}

// ---------------- fused clipping flash attention (swapped-operand) ----------------
// S^T = mfma(K,Q) -> C[k][q]: lane owns q-col (l15), k in regs -> lane-local softmax.
// O^T = mfma(Vt,P) -> C[d][q]: rescale/stats lane-local. K/V double-buffered.

__global__ __launch_bounds__(256) void attn_k(const u16* __restrict__ Qb,
                                              const u16* __restrict__ Kb,
                                              const u16* __restrict__ Vtb,
                                              const float* __restrict__ pm,
                                              const float* __restrict__ pmrow,
                                              const float* __restrict__ lamp,
                                              u16* __restrict__ Ob) {
  __shared__ __align__(16) u16 Ks[2][64*64];   // [k][d], XOR-swizzled chunks
  __shared__ __align__(16) u16 Vs[2][64*64];   // [d][k], XOR-swizzled chunks
  __shared__ __align__(16) u16 Ps[4][32*72];   // per-wave P [q][k], pad 72
  // XCD swizzle over linear id (nwg=1024)
  const int id0 = blockIdx.y * gridDim.x + blockIdx.x;
  const int id = (id0 & 7) * 128 + (id0 >> 3);
  const int bh = id & 63, qt = id >> 6;
  const int b = bh >> 4, h = bh & 15;
  const int tid = threadIdx.x, wave = tid >> 6, lane = tid & 63;
  const int g = lane >> 4, l15 = lane & 15;
  const float lam = lamp[b];
  const bool clip_en = lam > 1.0f;
  const int q0 = qt * 128 + wave * 32;       // seq-local q base for this wave

  // Q as B-operand frags: B[col=l15 -> q][t=g*8+j -> d]
  s16x8 qf[2][2];
  #pragma unroll
  for (int mi = 0; mi < 2; ++mi)
    #pragma unroll
    for (int kk = 0; kk < 2; ++kk)
      qf[mi][kk] = *(const s16x8*)&Qb[(size_t)(b*SEQ + q0 + mi*16 + l15)*D_MODEL + h*HD + kk*32 + g*8];

  // lane-local per-q stats (q = q0 + mi*16 + l15)
  float thr[2], mrow[2], lrow[2];
  #pragma unroll
  for (int mi = 0; mi < 2; ++mi) {
    thr[mi] = clip_en ? lam * pmrow[q0 + mi*16 + l15] : -INFINITY;
    mrow[mi] = -INFINITY;
    lrow[mi] = 0.0f;
  }
  f32x4 oacc[2][4] = {};   // O^T frags: [q-subtile mi][d-subtile di], C[d][q]

  #define STAGE(buf, kt) do {                                                   \
    _Pragma("unroll")                                                           \
    for (int c = 0; c < 2; ++c) {                                               \
      int chunk = wave * 2048 + c * 1024;                                       \
      int li = chunk + lane * 16;                                               \
      int r_ = li >> 7;                                                         \
      int ccol = (li & 127) >> 4;                                               \
      int gcol = ((ccol ^ (r_ & 7)) * 8);                                       \
      const u16* gk = Kb  + (size_t)(b*SEQ + (kt) + r_)*D_MODEL + h*HD + gcol;  \
      gload_lds16(gk, (char*)Ks[buf] + chunk);                                  \
      const u16* gv = Vtb + (size_t)(h*HD + r_)*ROWS + b*SEQ + (kt) + gcol;     \
      gload_lds16(gv, (char*)Vs[buf] + chunk);                                  \
    } } while (0)

  STAGE(0, 0);
  __syncthreads();
  int cur = 0;

  for (int kt = 0; kt < SEQ; kt += 64) {
    if (kt + 64 < SEQ) STAGE(cur ^ 1, kt + 64);

    // S^T = K Q^T : C[k][q]
    f32x4 s[2][4] = {};
    #pragma unroll
    for (int nj = 0; nj < 4; ++nj) {
      int row = nj*16 + l15;
      s16x8 kf0 = *(const s16x8*)((const char*)Ks[cur] + row*128 + (((0*4 + g) ^ (row & 7)) * 16));
      s16x8 kf1 = *(const s16x8*)((const char*)Ks[cur] + row*128 + (((1*4 + g) ^ (row & 7)) * 16));
      __builtin_amdgcn_s_setprio(1);
      #pragma unroll
      for (int mi = 0; mi < 2; ++mi) {
        s[mi][nj] = MFMA16(kf0, qf[mi][0], s[mi][nj], 0, 0, 0);
        s[mi][nj] = MFMA16(kf1, qf[mi][1], s[mi][nj], 0, 0, 0);
      }
      __builtin_amdgcn_s_setprio(0);
    }

    // lane-local softmax per q-subtile; k = nj*16 + g*4 + r (consecutive per reg)
    #pragma unroll
    for (int mi = 0; mi < 2; ++mi) {
      const int qrow = q0 + mi*16 + l15;
      const float* pmr = pm + (size_t)qrow * SEQ + kt;
      float Lv[4][4];
      float mx = -INFINITY;
      #pragma unroll
      for (int nj = 0; nj < 4; ++nj) {
        float4 pv = *(const float4*)(pmr + nj*16 + g*4);
        float pa[4] = {pv.x, pv.y, pv.z, pv.w};
        #pragma unroll
        for (int r = 0; r < 4; ++r) {
          float L = s[mi][nj][r] * 0.125f + lam * pa[r];
          L = (L < thr[mi]) ? -INFINITY : L;
          Lv[nj][r] = L;
          mx = fmaxf(mx, L);
        }
      }
      mx = fmaxf(mx, __shfl_xor(mx, 16));
      mx = fmaxf(mx, __shfl_xor(mx, 32));
      float mnew = fmaxf(mrow[mi], mx);
      float rs = 0.0f, scale;
      if (mnew == -INFINITY) {
        scale = 1.0f;
        #pragma unroll
        for (int nj = 0; nj < 4; ++nj)
          #pragma unroll
          for (int r = 0; r < 4; ++r) Lv[nj][r] = 0.0f;
      } else {
        scale = __expf(mrow[mi] - mnew);   // exp(-inf)=0 on first tile
        #pragma unroll
        for (int nj = 0; nj < 4; ++nj)
          #pragma unroll
          for (int r = 0; r < 4; ++r) {
            float p = __expf(Lv[nj][r] - mnew);
            Lv[nj][r] = p;
            rs += p;
          }
      }
      rs += __shfl_xor(rs, 16);
      rs += __shfl_xor(rs, 32);
      lrow[mi] = lrow[mi] * scale + rs;
      mrow[mi] = mnew;
      #pragma unroll
      for (int di = 0; di < 4; ++di)
        #pragma unroll
        for (int r = 0; r < 4; ++r) oacc[mi][di][r] *= scale;
      // pack P -> LDS: row q (=mi*16+l15), 4 consecutive k per write (b64)
      #pragma unroll
      for (int nj = 0; nj < 4; ++nj) {
        u32 d0 = cvt_pk_bf16(Lv[nj][0], Lv[nj][1]);
        u32 d1 = cvt_pk_bf16(Lv[nj][2], Lv[nj][3]);
        u64 w = (u64)d0 | ((u64)d1 << 32);
        *(u64*)&Ps[wave][(mi*16 + l15)*72 + nj*16 + g*4] = w;
      }
    }

    // O^T += Vt P^T : C[d][q];  A=Vt-frag (rows d), B=P-frag (cols q)
    s16x8 pf[2][2];
    #pragma unroll
    for (int mi = 0; mi < 2; ++mi)
      #pragma unroll
      for (int kk = 0; kk < 2; ++kk)
        pf[mi][kk] = *(const s16x8*)&Ps[wave][(mi*16 + l15)*72 + kk*32 + g*8];
    s16x8 vf[4][2];
    #pragma unroll
    for (int di = 0; di < 4; ++di) {
      int row = di*16 + l15;
      #pragma unroll
      for (int kk = 0; kk < 2; ++kk)
        vf[di][kk] = *(const s16x8*)((const char*)Vs[cur] + row*128 + (((kk*4 + g) ^ (row & 7)) * 16));
    }
    __builtin_amdgcn_s_setprio(1);
    #pragma unroll
    for (int mi = 0; mi < 2; ++mi)
      #pragma unroll
      for (int di = 0; di < 4; ++di)
        #pragma unroll
        for (int kk = 0; kk < 2; ++kk)
          oacc[mi][di] = MFMA16(vf[di][kk], pf[mi][kk], oacc[mi][di], 0, 0, 0);
    __builtin_amdgcn_s_setprio(0);
    __syncthreads();   // drains STAGE vmcnt + guards K/V buffer swap
    cur ^= 1;
  }
  #undef STAGE

  // epilogue: O^T frag (row = d-local g*4+r, col = q-local l15) -> Ob[q][d]
  #pragma unroll
  for (int mi = 0; mi < 2; ++mi) {
    float inv = 1.0f / lrow[mi];
    size_t base = (size_t)(b*SEQ + q0 + mi*16 + l15) * D_MODEL + h*HD;
    #pragma unroll
    for (int di = 0; di < 4; ++di) {
      u32 d0 = cvt_pk_bf16(oacc[mi][di][0] * inv, oacc[mi][di][1] * inv);
      u32 d1 = cvt_pk_bf16(oacc[mi][di][2] * inv, oacc[mi][di][3] * inv);
      u64 w = (u64)d0 | ((u64)d1 << 32);
      *(u64*)&Ob[base + di*16 + g*4] = w;
    }
  }
}

// ---------------- launcher ----------------

extern "C" void kernel_launch(void* const* d_in, const int* in_sizes, int n_in,
                              void* d_out, int out_size, void* d_ws, size_t ws_size,
                              hipStream_t stream) {
  const float* x  = (const float*)d_in[0];
  const float* pm = (const float*)d_in[1];
  const float* dx = (const float*)d_in[2];
  const float* wq = (const float*)d_in[3];
  const float* bq = (const float*)d_in[4];
  const float* wk = (const float*)d_in[5];
  const float* bk = (const float*)d_in[6];
  const float* wv = (const float*)d_in[7];
  const float* bv = (const float*)d_in[8];
  const float* wo = (const float*)d_in[9];
  const float* bo = (const float*)d_in[10];
  float* out = (float*)d_out;

  char* ws = (char*)d_ws;
  const size_t MB = 1024 * 1024;
  u16* xb   = (u16*)(ws + 0 * MB);
  u16* Qb   = (u16*)(ws + 16 * MB);
  u16* Kb   = (u16*)(ws + 32 * MB);
  u16* Vtb  = (u16*)(ws + 48 * MB);
  u16* Obuf = (u16*)(ws + 64 * MB);
  u16* wqb  = (u16*)(ws + 80 * MB);
  u16* wkb  = (u16*)(ws + 82 * MB);
  u16* wvb  = (u16*)(ws + 84 * MB);
  u16* wob  = (u16*)(ws + 86 * MB);
  float* pmrow = (float*)(ws + 88 * MB);
  float* usum  = (float*)(ws + 88 * MB + 16384);
  float* lam   = (float*)(ws + 88 * MB + 16384 + 64);

  hipMemsetAsync(usum, 0, 16, stream);
  cast_f32_bf16<<<8192, 256, 0, stream>>>(x,  xb,  ROWS * D_MODEL / 4);
  cast_f32_bf16<<<1024, 256, 0, stream>>>(wq, wqb, D_MODEL * D_MODEL / 4);
  cast_f32_bf16<<<1024, 256, 0, stream>>>(wk, wkb, D_MODEL * D_MODEL / 4);
  cast_f32_bf16<<<1024, 256, 0, stream>>>(wv, wvb, D_MODEL * D_MODEL / 4);
  cast_f32_bf16<<<1024, 256, 0, stream>>>(wo, wob, D_MODEL * D_MODEL / 4);
  row_u<<<ROWS, 256, 0, stream>>>(x, dx, usum);
  pm_rowmean_k<<<SEQ, 256, 0, stream>>>(pm, pmrow);
  lam_k<<<1, 64, 0, stream>>>(usum, lam);

  gemm_bt<u16, false><<<dim3(8, 64), 256, 0, stream>>>(xb, wqb, bq, Qb, ROWS, D_MODEL, D_MODEL);
  gemm_bt<u16, false><<<dim3(8, 64), 256, 0, stream>>>(xb, wkb, bk, Kb, ROWS, D_MODEL, D_MODEL);
  gemm_bt<u16, true ><<<dim3(64, 8), 256, 0, stream>>>(wvb, xb, bv, Vtb, D_MODEL, ROWS, D_MODEL);

  attn_k<<<dim3(64, 16), 256, 0, stream>>>(Qb, Kb, Vtb, pm, pmrow, lam, Obuf);

  gemm_bt<float, false><<<dim3(8, 64), 256, 0, stream>>>(Obuf, wob, bo, out, ROWS, D_MODEL, D_MODEL);
}

// Round 4
// 545.611 us; speedup vs baseline: 1.6412x; 1.1265x over previous
//
#include <hip/hip_runtime.h>
#include <hip/hip_bf16.h>

typedef unsigned short u16;
typedef unsigned int u32;
typedef unsigned long long u64;
typedef __attribute__((ext_vector_type(4))) float f32x4;
typedef __attribute__((ext_vector_type(8))) short s16x8;

#define D_MODEL 1024
#define NHEADS 16
#define HD 64
#define SEQ 2048
#define BATCH 4
#define ROWS (BATCH*SEQ)

#define MFMA16 __builtin_amdgcn_mfma_f32_16x16x32_bf16
#define LOG2E 1.4426950408889634f
#define THR2 11.5416f   /* defer-max threshold: 8.0 * log2(e) */

// round-to-nearest-even f32 -> bf16
__device__ inline u16 f2bf(float f) {
  u32 u = __builtin_bit_cast(u32, f);
  u32 r = (u + 0x7fffu + ((u >> 16) & 1u)) >> 16;
  return (u16)r;
}

// pack 2 f32 -> 1 dword of 2 bf16 (RNE)
__device__ inline u32 cvt_pk_bf16(float lo, float hi) {
  u32 r;
  asm volatile("v_cvt_pk_bf16_f32 %0, %1, %2" : "=v"(r) : "v"(lo), "v"(hi));
  return r;
}

__device__ inline void gload_lds16(const void* g, void* l) {
  __builtin_amdgcn_global_load_lds((const __attribute__((address_space(1))) void*)g,
                                   (__attribute__((address_space(3))) void*)l,
                                   16, 0, 0);
}

// ---------------- small kernels ----------------

__global__ __launch_bounds__(256) void cast_f32_bf16(const float* __restrict__ src,
                                                     u16* __restrict__ dst, int n4) {
  int i = blockIdx.x * 256 + threadIdx.x;
  if (i >= n4) return;
  float4 v = ((const float4*)src)[i];
  union { u16 s[4]; u64 ll; } o;
  o.s[0] = f2bf(v.x); o.s[1] = f2bf(v.y); o.s[2] = f2bf(v.z); o.s[3] = f2bf(v.w);
  ((u64*)dst)[i] = o.ll;
}

__global__ __launch_bounds__(256) void row_u(const float* __restrict__ x,
                                             const float* __restrict__ dx,
                                             float* __restrict__ usum) {
  int row = blockIdx.x;
  int tid = threadIdx.x;
  const float4* xr = (const float4*)(x + (size_t)row * D_MODEL);
  const float4* dr = (const float4*)(dx + (size_t)row * D_MODEL);
  float4 a = xr[tid], d = dr[tid];
  float sx = a.x*a.x + a.y*a.y + a.z*a.z + a.w*a.w;
  float sd = d.x*d.x + d.y*d.y + d.z*d.z + d.w*d.w;
  #pragma unroll
  for (int m = 1; m < 64; m <<= 1) { sx += __shfl_xor(sx, m); sd += __shfl_xor(sd, m); }
  __shared__ float rx[4], rd[4];
  int wave = tid >> 6;
  if ((tid & 63) == 0) { rx[wave] = sx; rd[wave] = sd; }
  __syncthreads();
  if (tid == 0) {
    float SX = rx[0]+rx[1]+rx[2]+rx[3];
    float SD = rd[0]+rd[1]+rd[2]+rd[3];
    float u = sqrtf(SD) / (sqrtf(SX) + 1e-8f);
    atomicAdd(&usum[row >> 11], u);
  }
}

__global__ __launch_bounds__(256) void pm_rowmean_k(const float* __restrict__ pm,
                                                    float* __restrict__ pmrow) {
  int row = blockIdx.x, tid = threadIdx.x;
  const float4* pr = (const float4*)(pm + (size_t)row * SEQ);
  float4 a = pr[tid*2], b = pr[tid*2+1];
  float s = a.x+a.y+a.z+a.w + b.x+b.y+b.z+b.w;
  #pragma unroll
  for (int m = 1; m < 64; m <<= 1) s += __shfl_xor(s, m);
  __shared__ float rs[4];
  int wave = tid >> 6;
  if ((tid & 63) == 0) rs[wave] = s;
  __syncthreads();
  if (tid == 0) pmrow[row] = (rs[0]+rs[1]+rs[2]+rs[3]) * (1.0f / SEQ);
}

__global__ void lam_k(const float* __restrict__ usum, float* __restrict__ lam) {
  int t = threadIdx.x;
  if (t < BATCH) lam[t] = 10.0f * expf(-5.0f * usum[t] * (1.0f / SEQ));
}

// ---------------- GEMM: C[i][j] = (sum_k A[i][k]*Bw[j][k] + bias) * oscale ----------
// 2-phase double-buffered (T3 minimum): STAGE(next) -> compute(cur) -> barrier.

__device__ inline void store_o(float* C, size_t i, float v) { C[i] = v; }
__device__ inline void store_o(u16* C, size_t i, float v)   { C[i] = f2bf(v); }

template<typename OutT, bool ROWB>
__global__ __launch_bounds__(256) void gemm_bt(const u16* __restrict__ A,
                                               const u16* __restrict__ Bw,
                                               const float* __restrict__ bias,
                                               OutT* __restrict__ C,
                                               int M, int N, int K, float oscale) {
  __shared__ __align__(16) u16 As[2][128*32];
  __shared__ __align__(16) u16 Bs[2][128*32];
  const int tid = threadIdx.x;
  const int wave = tid >> 6, lane = tid & 63, g = lane >> 4, l15 = lane & 15;
  // XCD-aware swizzle (nwg % 8 == 0 for all our grids)
  const int id0 = blockIdx.y * gridDim.x + blockIdx.x;
  const int cpx = (gridDim.x * gridDim.y) >> 3;
  const int id = (id0 & 7) * cpx + (id0 >> 3);
  const int bx = id % gridDim.x, by = id / gridDim.x;
  const int row0 = by * 128, col0 = bx * 128;
  const int wr = (wave >> 1) * 64, wc = (wave & 1) * 64;
  f32x4 acc[4][4] = {};
  const int chunk0 = wave * 2048;

  #define GSTAGE(buf, k0) do {                                          \
    _Pragma("unroll")                                                   \
    for (int c = 0; c < 2; ++c) {                                       \
      int chunk = chunk0 + c * 1024;                                    \
      int li = chunk + lane * 16;                                       \
      int r_ = li >> 6;                                                 \
      int cb = (li & 63) >> 1;                                          \
      gload_lds16(A  + (size_t)(row0 + r_) * K + (k0) + cb, (char*)As[buf] + chunk); \
      gload_lds16(Bw + (size_t)(col0 + r_) * K + (k0) + cb, (char*)Bs[buf] + chunk); \
    } } while (0)

  GSTAGE(0, 0);
  __syncthreads();
  int cur = 0;
  for (int k0 = 0; k0 < K; k0 += 32) {
    if (k0 + 32 < K) GSTAGE(cur ^ 1, k0 + 32);
    s16x8 af[4], bf[4];
    #pragma unroll
    for (int mi = 0; mi < 4; ++mi) af[mi] = *(const s16x8*)&As[cur][(wr + mi*16 + l15)*32 + g*8];
    #pragma unroll
    for (int ni = 0; ni < 4; ++ni) bf[ni] = *(const s16x8*)&Bs[cur][(wc + ni*16 + l15)*32 + g*8];
    __builtin_amdgcn_s_setprio(1);
    #pragma unroll
    for (int mi = 0; mi < 4; ++mi)
      #pragma unroll
      for (int ni = 0; ni < 4; ++ni)
        acc[mi][ni] = MFMA16(af[mi], bf[ni], acc[mi][ni], 0, 0, 0);
    __builtin_amdgcn_s_setprio(0);
    __syncthreads();   // drains vmcnt (next buf filled) + guards reuse of cur
    cur ^= 1;
  }
  #undef GSTAGE

  #pragma unroll
  for (int mi = 0; mi < 4; ++mi) {
    int rbase = row0 + wr + mi*16 + g*4;
    #pragma unroll
    for (int ni = 0; ni < 4; ++ni) {
      int cc = col0 + wc + ni*16 + l15;
      float cbias = ROWB ? 0.0f : bias[cc];
      #pragma unroll
      for (int r = 0; r < 4; ++r) {
        float v = (acc[mi][ni][r] + (ROWB ? bias[rbase + r] : cbias)) * oscale;
        store_o(C, (size_t)(rbase + r) * N + cc, v);
      }
    }
  }
}

// ---------------- fused clipping flash attention (swapped-operand, exp2 domain) ----
// Qb pre-scaled by 0.125*log2e. S2 = mfma(K,Q) -> C[k][q]: lane owns q (l15), k in
// regs. L2 = S2 + lam2*pm; p = exp2(L2 - m). Defer-max (T13). K/V double-buffered.

__global__ __launch_bounds__(256) void attn_k(const u16* __restrict__ Qb,
                                              const u16* __restrict__ Kb,
                                              const u16* __restrict__ Vtb,
                                              const float* __restrict__ pm,
                                              const float* __restrict__ pmrow,
                                              const float* __restrict__ lamp,
                                              u16* __restrict__ Ob) {
  __shared__ __align__(16) u16 Ks[2][64*64];   // [k][d], XOR-swizzled chunks
  __shared__ __align__(16) u16 Vs[2][64*64];   // [d][k], XOR-swizzled chunks
  __shared__ __align__(16) u16 Ps[4][32*72];   // per-wave P [q][k], pad 72
  const int id0 = blockIdx.y * gridDim.x + blockIdx.x;
  const int id = (id0 & 7) * 128 + (id0 >> 3);
  const int bh = id & 63, qt = id >> 6;
  const int b = bh >> 4, h = bh & 15;
  const int tid = threadIdx.x, wave = tid >> 6, lane = tid & 63;
  const int g = lane >> 4, l15 = lane & 15;
  const float lam = lamp[b];
  const float lam2 = lam * LOG2E;
  const bool clip_en = lam > 1.0f;
  const int q0 = qt * 128 + wave * 32;

  s16x8 qf[2][2];
  #pragma unroll
  for (int mi = 0; mi < 2; ++mi)
    #pragma unroll
    for (int kk = 0; kk < 2; ++kk)
      qf[mi][kk] = *(const s16x8*)&Qb[(size_t)(b*SEQ + q0 + mi*16 + l15)*D_MODEL + h*HD + kk*32 + g*8];

  // lane-local per-q stats (q = q0 + mi*16 + l15), log2 domain
  float thr[2], mrow[2], lrow[2];
  #pragma unroll
  for (int mi = 0; mi < 2; ++mi) {
    thr[mi] = clip_en ? lam2 * pmrow[q0 + mi*16 + l15] : -INFINITY;
    mrow[mi] = -INFINITY;
    lrow[mi] = 0.0f;
  }
  f32x4 oacc[2][4] = {};

  #define STAGE(buf, kt) do {                                                   \
    _Pragma("unroll")                                                           \
    for (int c = 0; c < 2; ++c) {                                               \
      int chunk = wave * 2048 + c * 1024;                                       \
      int li = chunk + lane * 16;                                               \
      int r_ = li >> 7;                                                         \
      int ccol = (li & 127) >> 4;                                               \
      int gcol = ((ccol ^ (r_ & 7)) * 8);                                       \
      const u16* gk = Kb  + (size_t)(b*SEQ + (kt) + r_)*D_MODEL + h*HD + gcol;  \
      gload_lds16(gk, (char*)Ks[buf] + chunk);                                  \
      const u16* gv = Vtb + (size_t)(h*HD + r_)*ROWS + b*SEQ + (kt) + gcol;     \
      gload_lds16(gv, (char*)Vs[buf] + chunk);                                  \
    } } while (0)

  STAGE(0, 0);
  __syncthreads();
  int cur = 0;

  for (int kt = 0; kt < SEQ; kt += 64) {
    if (kt + 64 < SEQ) STAGE(cur ^ 1, kt + 64);

    // hoist pm loads so their latency hides under QK^T MFMA
    float4 pv[2][4];
    #pragma unroll
    for (int mi = 0; mi < 2; ++mi) {
      const float* pmr = pm + (size_t)(q0 + mi*16 + l15) * SEQ + kt;
      #pragma unroll
      for (int nj = 0; nj < 4; ++nj)
        pv[mi][nj] = *(const float4*)(pmr + nj*16 + g*4);
    }

    // S2^T = K Q^T : C[k][q], k = nj*16 + g*4 + r
    f32x4 s[2][4] = {};
    #pragma unroll
    for (int nj = 0; nj < 4; ++nj) {
      int row = nj*16 + l15;
      s16x8 kf0 = *(const s16x8*)((const char*)Ks[cur] + row*128 + ((g ^ (row & 7)) * 16));
      s16x8 kf1 = *(const s16x8*)((const char*)Ks[cur] + row*128 + (((4 + g) ^ (row & 7)) * 16));
      __builtin_amdgcn_s_setprio(1);
      #pragma unroll
      for (int mi = 0; mi < 2; ++mi) {
        s[mi][nj] = MFMA16(kf0, qf[mi][0], s[mi][nj], 0, 0, 0);
        s[mi][nj] = MFMA16(kf1, qf[mi][1], s[mi][nj], 0, 0, 0);
      }
      __builtin_amdgcn_s_setprio(0);
    }

    // lane-local softmax (log2 domain) + defer-max
    #pragma unroll
    for (int mi = 0; mi < 2; ++mi) {
      float mx = -INFINITY;
      #pragma unroll
      for (int nj = 0; nj < 4; ++nj) {
        float pa[4] = {pv[mi][nj].x, pv[mi][nj].y, pv[mi][nj].z, pv[mi][nj].w};
        #pragma unroll
        for (int r = 0; r < 4; ++r) {
          float L = fmaf(lam2, pa[r], s[mi][nj][r]);
          s[mi][nj][r] = L;
          mx = fmaxf(mx, L);
        }
      }
      mx = fmaxf(mx, __shfl_xor(mx, 16));
      mx = fmaxf(mx, __shfl_xor(mx, 32));
      // raw max == unclipped max whenever any element survives (clip removes
      // only below-threshold values); all-clipped tiles get rs=0 regardless.
      if (__any(mx > mrow[mi] + THR2)) {
        float mnew = fmaxf(mrow[mi], mx);
        float scale = __builtin_amdgcn_exp2f(mrow[mi] - mnew);  // -inf -> 0
        lrow[mi] *= scale;
        #pragma unroll
        for (int di = 0; di < 4; ++di)
          #pragma unroll
          for (int r = 0; r < 4; ++r) oacc[mi][di][r] *= scale;
        mrow[mi] = mnew;
      }
      const float m = mrow[mi];
      float rs = 0.0f;
      #pragma unroll
      for (int nj = 0; nj < 4; ++nj)
        #pragma unroll
        for (int r = 0; r < 4; ++r) {
          float L = s[mi][nj][r];
          float p = (L < thr[mi]) ? 0.0f : __builtin_amdgcn_exp2f(L - m);
          s[mi][nj][r] = p;
          rs += p;
        }
      rs += __shfl_xor(rs, 16);
      rs += __shfl_xor(rs, 32);
      lrow[mi] += rs;
      // pack P -> LDS: row q, 4 consecutive k per b64 write
      #pragma unroll
      for (int nj = 0; nj < 4; ++nj) {
        u32 d0 = cvt_pk_bf16(s[mi][nj][0], s[mi][nj][1]);
        u32 d1 = cvt_pk_bf16(s[mi][nj][2], s[mi][nj][3]);
        u64 w = (u64)d0 | ((u64)d1 << 32);
        *(u64*)&Ps[wave][(mi*16 + l15)*72 + nj*16 + g*4] = w;
      }
    }

    // O^T += Vt P^T : C[d][q]
    s16x8 pf[2][2];
    #pragma unroll
    for (int mi = 0; mi < 2; ++mi)
      #pragma unroll
      for (int kk = 0; kk < 2; ++kk)
        pf[mi][kk] = *(const s16x8*)&Ps[wave][(mi*16 + l15)*72 + kk*32 + g*8];
    s16x8 vf[4][2];
    #pragma unroll
    for (int di = 0; di < 4; ++di) {
      int row = di*16 + l15;
      #pragma unroll
      for (int kk = 0; kk < 2; ++kk)
        vf[di][kk] = *(const s16x8*)((const char*)Vs[cur] + row*128 + (((kk*4 + g) ^ (row & 7)) * 16));
    }
    __builtin_amdgcn_s_setprio(1);
    #pragma unroll
    for (int mi = 0; mi < 2; ++mi)
      #pragma unroll
      for (int di = 0; di < 4; ++di)
        #pragma unroll
        for (int kk = 0; kk < 2; ++kk)
          oacc[mi][di] = MFMA16(vf[di][kk], pf[mi][kk], oacc[mi][di], 0, 0, 0);
    __builtin_amdgcn_s_setprio(0);
    __syncthreads();
    cur ^= 1;
  }
  #undef STAGE

  #pragma unroll
  for (int mi = 0; mi < 2; ++mi) {
    float inv = 1.0f / lrow[mi];
    size_t base = (size_t)(b*SEQ + q0 + mi*16 + l15) * D_MODEL + h*HD;
    #pragma unroll
    for (int di = 0; di < 4; ++di) {
      u32 d0 = cvt_pk_bf16(oacc[mi][di][0] * inv, oacc[mi][di][1] * inv);
      u32 d1 = cvt_pk_bf16(oacc[mi][di][2] * inv, oacc[mi][di][3] * inv);
      u64 w = (u64)d0 | ((u64)d1 << 32);
      *(u64*)&Ob[base + di*16 + g*4] = w;
    }
  }
}

// ---------------- launcher ----------------

extern "C" void kernel_launch(void* const* d_in, const int* in_sizes, int n_in,
                              void* d_out, int out_size, void* d_ws, size_t ws_size,
                              hipStream_t stream) {
  const float* x  = (const float*)d_in[0];
  const float* pm = (const float*)d_in[1];
  const float* dx = (const float*)d_in[2];
  const float* wq = (const float*)d_in[3];
  const float* bq = (const float*)d_in[4];
  const float* wk = (const float*)d_in[5];
  const float* bk = (const float*)d_in[6];
  const float* wv = (const float*)d_in[7];
  const float* bv = (const float*)d_in[8];
  const float* wo = (const float*)d_in[9];
  const float* bo = (const float*)d_in[10];
  float* out = (float*)d_out;

  char* ws = (char*)d_ws;
  const size_t MB = 1024 * 1024;
  u16* xb   = (u16*)(ws + 0 * MB);
  u16* Qb   = (u16*)(ws + 16 * MB);
  u16* Kb   = (u16*)(ws + 32 * MB);
  u16* Vtb  = (u16*)(ws + 48 * MB);
  u16* Obuf = (u16*)(ws + 64 * MB);
  u16* wqb  = (u16*)(ws + 80 * MB);
  u16* wkb  = (u16*)(ws + 82 * MB);
  u16* wvb  = (u16*)(ws + 84 * MB);
  u16* wob  = (u16*)(ws + 86 * MB);
  float* pmrow = (float*)(ws + 88 * MB);
  float* usum  = (float*)(ws + 88 * MB + 16384);
  float* lam   = (float*)(ws + 88 * MB + 16384 + 64);

  const float QSCALE = 0.125f * LOG2E;   // folded into Q projection output

  hipMemsetAsync(usum, 0, 16, stream);
  cast_f32_bf16<<<8192, 256, 0, stream>>>(x,  xb,  ROWS * D_MODEL / 4);
  cast_f32_bf16<<<1024, 256, 0, stream>>>(wq, wqb, D_MODEL * D_MODEL / 4);
  cast_f32_bf16<<<1024, 256, 0, stream>>>(wk, wkb, D_MODEL * D_MODEL / 4);
  cast_f32_bf16<<<1024, 256, 0, stream>>>(wv, wvb, D_MODEL * D_MODEL / 4);
  cast_f32_bf16<<<1024, 256, 0, stream>>>(wo, wob, D_MODEL * D_MODEL / 4);
  row_u<<<ROWS, 256, 0, stream>>>(x, dx, usum);
  pm_rowmean_k<<<SEQ, 256, 0, stream>>>(pm, pmrow);
  lam_k<<<1, 64, 0, stream>>>(usum, lam);

  gemm_bt<u16, false><<<dim3(8, 64), 256, 0, stream>>>(xb, wqb, bq, Qb, ROWS, D_MODEL, D_MODEL, QSCALE);
  gemm_bt<u16, false><<<dim3(8, 64), 256, 0, stream>>>(xb, wkb, bk, Kb, ROWS, D_MODEL, D_MODEL, 1.0f);
  gemm_bt<u16, true ><<<dim3(64, 8), 256, 0, stream>>>(wvb, xb, bv, Vtb, D_MODEL, ROWS, D_MODEL, 1.0f);

  attn_k<<<dim3(64, 16), 256, 0, stream>>>(Qb, Kb, Vtb, pm, pmrow, lam, Obuf);

  gemm_bt<float, false><<<dim3(8, 64), 256, 0, stream>>>(Obuf, wob, bo, out, ROWS, D_MODEL, D_MODEL, 1.0f);
}